// Round 2
// baseline (314.298 us; speedup 1.0000x reference)
//
#include <hip/hip_runtime.h>

// Reference: result = items (4M x 2 x 2 x 3 fp32) passthrough; final_pool = items[:1024].
// d_out = [ in[0:48,000,000) , in[0:12,288) ]  — pure D2D copy, memory-bound.
// Mandatory traffic: 192 MB read + 192 MB write ≈ 384 MB → ~60 us at 6.3-6.6 TB/s
// (harness's own fills sustain 6.6 TB/s on these buffers).
//
// Use the ROCm blit path (hipMemcpyAsync D2D — graph-capture legal, becomes a
// memcpy node) instead of a hand-rolled kernel: best-tuned streaming copy
// available, zero index-arithmetic overhead.

#define N_MAIN 48000000LL   // 4,000,000 * 2 * 2 * 3 floats
#define N_TAIL 12288LL      // 1024 * 12 floats

extern "C" void kernel_launch(void* const* d_in, const int* in_sizes, int n_in,
                              void* d_out, int out_size, void* d_ws, size_t ws_size,
                              hipStream_t stream) {
    const float* in = (const float*)d_in[0];
    float* out = (float*)d_out;

    // Main passthrough: out[0 : 48e6) = in[0 : 48e6)
    hipMemcpyAsync(out, in, (size_t)N_MAIN * sizeof(float),
                   hipMemcpyDeviceToDevice, stream);
    // Tail: out[48e6 : 48e6 + 12288) = in[0 : 12288)  (48 KB, L2-hot)
    hipMemcpyAsync(out + N_MAIN, in, (size_t)N_TAIL * sizeof(float),
                   hipMemcpyDeviceToDevice, stream);
}